// Round 1
// 87.193 us; speedup vs baseline: 1.1160x; 1.1160x over previous
//
#include <hip/hip_runtime.h>
#include <cmath>

#define HW (512*512)
#define NSUB 2048            // 64 bins x 32 sub-bins
#define THREADS1 1024
#define BLKS_PER_IMG 32
#define PART_WORDS (3 * NSUB / 2)   // 3072 u32 per partial (u16-packed sub-bins)

__device__ __forceinline__ float fexp2(float x) { return __builtin_amdgcn_exp2f(x); }
__device__ __forceinline__ float flog2(float x) { return __builtin_amdgcn_logf(x); }

// Phase 1: RGB -> Lab -> integer sub-bin counting into dual wave-parity LDS
// tables (3 ds_add_u32 per pixel). Per-block partial tables written to ws as
// packed u16 pairs (plain coalesced u32 stores; max count/block = 8192 < 2^16).
__global__ __launch_bounds__(THREADS1) void count_kernel(const float* __restrict__ img,
                                                         unsigned* __restrict__ part) {
    __shared__ unsigned sh[2][3 * NSUB];   // 48 KB
    const int tid = threadIdx.x;
    unsigned* flat = &sh[0][0];
    for (int i = tid; i < 2 * 3 * NSUB; i += THREADS1) flat[i] = 0u;
    __syncthreads();

    unsigned* h = sh[(tid >> 6) & 1];      // wave parity selects table

    const int b  = blockIdx.y;
    const int bx = blockIdx.x;
    const float* base = img + (size_t)b * 3u * HW;

    const int stride = BLKS_PER_IMG * THREADS1 * 4;
    for (int p = (bx * THREADS1 + tid) * 4; p < HW; p += stride) {
        float4 r4 = *reinterpret_cast<const float4*>(base + p);
        float4 g4 = *reinterpret_cast<const float4*>(base + p + HW);
        float4 b4 = *reinterpret_cast<const float4*>(base + p + 2 * HW);
        float rr[4] = {r4.x, r4.y, r4.z, r4.w};
        float gg[4] = {g4.x, g4.y, g4.z, g4.w};
        float bl[4] = {b4.x, b4.y, b4.z, b4.w};

        #pragma unroll
        for (int k = 0; k < 4; ++k) {
            // sRGB -> linear (inputs to log2 provably >= 0.052: no denormal risk)
            float lr = (rr[k] > 0.04045f) ? fexp2(2.4f * flog2((rr[k] + 0.055f) * (1.0f / 1.055f))) : rr[k] * (1.0f / 12.92f);
            float lg = (gg[k] > 0.04045f) ? fexp2(2.4f * flog2((gg[k] + 0.055f) * (1.0f / 1.055f))) : gg[k] * (1.0f / 12.92f);
            float lb = (bl[k] > 0.04045f) ? fexp2(2.4f * flog2((bl[k] + 0.055f) * (1.0f / 1.055f))) : bl[k] * (1.0f / 12.92f);

            // XYZ with xn/zn folded into the matrix rows
            float x = 0.4339530f * lr + 0.3762197f * lg + 0.1898288f * lb; // x/0.950456
            float y = 0.2126710f * lr + 0.7151600f * lg + 0.0721690f * lb;
            float z = 0.0177578f * lr + 0.1094766f * lg + 0.8727661f * lb; // z/1.088754

            // f(t): cbrt path inputs > 0.008856: no denormal risk
            float fx = (x > 0.008856f) ? fexp2(flog2(x) * (1.0f/3.0f)) : 7.787f * x + 16.0f/116.0f;
            float fy = (y > 0.008856f) ? fexp2(flog2(y) * (1.0f/3.0f)) : 7.787f * y + 16.0f/116.0f;
            float fz = (z > 0.008856f) ? fexp2(flog2(z) * (1.0f/3.0f)) : 7.787f * z + 16.0f/116.0f;

            // sub-bin indices (scale/offset folded); ranges provably in [0,2048)
            int iL = (int)(2375.68f    * fy - 327.68f);
            int iA = (int)(4015.6863f  * (fx - fy) + 1028.01569f);
            int iB = (int)(1606.27451f * (fy - fz) + 1028.01569f);

            atomicAdd(&h[iL], 1u);
            atomicAdd(&h[NSUB + iA], 1u);
            atomicAdd(&h[2 * NSUB + iB], 1u);
        }
    }
    __syncthreads();

    // merge dual tables -> per-block partial, packed as u16 pairs (coalesced u32 stores)
    unsigned* dst = part + (size_t)(b * BLKS_PER_IMG + bx) * PART_WORDS;
    for (int i = tid; i < PART_WORDS; i += THREADS1) {
        unsigned s0 = sh[0][2 * i]     + sh[1][2 * i];       // <= 8192, fits u16
        unsigned s1 = sh[0][2 * i + 1] + sh[1][2 * i + 1];
        dst[i] = s0 | (s1 << 16);
    }
}

// Phase 2: reduce 32 u16-packed partials (1024 threads: 1 packed word each ->
// 4x the MLP of the old 256-thread version, half the bytes), then truncated
// Gaussian conv -> 64 bins (16 lanes/bin, identical 204-tap window), normalize.
__global__ __launch_bounds__(1024) void conv_norm_kernel(const unsigned* __restrict__ part,
                                                         float* __restrict__ out) {
    __shared__ float sub[NSUB];
    __shared__ float hb[64];
    const int img = blockIdx.x / 3;
    const int ch  = blockIdx.x % 3;
    const int t   = threadIdx.x;           // u32 word index 0..1023 within channel

    const unsigned* p0 = part + (size_t)img * BLKS_PER_IMG * PART_WORDS
                              + (size_t)ch * (NSUB / 2) + t;
    unsigned s0 = 0, s1 = 0;
    #pragma unroll
    for (int k = 0; k < BLKS_PER_IMG; ++k) {
        unsigned v = p0[(size_t)k * PART_WORDS];
        s0 += v & 0xFFFFu;
        s1 += v >> 16;
    }
    sub[2 * t]     = (float)s0;            // exact: integer sums < 2^24
    sub[2 * t + 1] = (float)s1;
    __syncthreads();

    // d(s,j) = (s+0.5)/32 - 0.5 - j; 204 taps: s in [32j-86, 32j+117]
    const int j = t >> 4;                  // bin 0..63
    const int q = t & 15;                  // 16 lanes per bin
    const float C = 2.8853901f;            // 2/ln2
    const float jf = (float)j + 0.5f - (0.5f / 32.0f);
    const int s_lo = 32 * j - 86;
    float acc = 0.0f;
    #pragma unroll
    for (int i = 0; i < 13; ++i) {
        int s = s_lo + q + 16 * i;
        if (s < s_lo + 204 && (unsigned)s < (unsigned)NSUB) {
            float d = (float)s * (1.0f / 32.0f) - jf;
            acc += sub[s] * fexp2(-C * d * d);
        }
    }
    acc += __shfl_xor(acc, 1, 64);
    acc += __shfl_xor(acc, 2, 64);
    acc += __shfl_xor(acc, 4, 64);
    acc += __shfl_xor(acc, 8, 64);
    if (q == 0) hb[j] = acc;
    __syncthreads();

    if (t < 64) {
        float v = hb[t];
        float s = v;
        #pragma unroll
        for (int off = 32; off >= 1; off >>= 1) s += __shfl_down(s, off, 64);
        s = __shfl(s, 0, 64);
        out[img * 192 + ch * 64 + t] = v / (s + 1e-8f);
    }
}

extern "C" void kernel_launch(void* const* d_in, const int* in_sizes, int n_in,
                              void* d_out, int out_size, void* d_ws, size_t ws_size,
                              hipStream_t stream) {
    const float* img = (const float*)d_in[0];
    float* out     = (float*)d_out;
    unsigned* part = (unsigned*)d_ws;     // 16*32 partials * 3072 u32 = 6.3 MB

    const int B = in_sizes[0] / (3 * HW); // 16

    count_kernel<<<dim3(BLKS_PER_IMG, B), THREADS1, 0, stream>>>(img, part);
    conv_norm_kernel<<<B * 3, 1024, 0, stream>>>(part, out);
}